// Round 5
// baseline (389.887 us; speedup 1.0000x reference)
//
#include <hip/hip_runtime.h>
#include <hip/hip_bf16.h>

#define NQ    2000      // B*L
#define KDIM  8192      // G*P*ch = 4*32*64
#define EMB   256
#define MPAD  2048      // NQ padded for GEMM tiles
#define SPLITK 8

typedef __attribute__((ext_vector_type(8))) short bf16x8;
typedef __attribute__((ext_vector_type(4))) float f32x4;
typedef __attribute__((ext_vector_type(2))) float f32x2;

__device__ __forceinline__ float sigf(float x) { return 1.0f / (1.0f + __expf(-x)); }

__device__ __forceinline__ unsigned short f2bf(float x) {
    union { float f; unsigned int u; } v; v.f = x;
    unsigned int r = v.u + 0x7fffu + ((v.u >> 16) & 1u);
    return (unsigned short)(r >> 16);
}
__device__ __forceinline__ float bf2f(unsigned short h) {
    union { unsigned int u; float f; } v; v.u = ((unsigned int)h) << 16; return v.f;
}
// pack two fp32 -> two bf16 (RNE) in one dword (v_cvt_pk_bf16_f32 on gfx950)
__device__ __forceinline__ unsigned int pkbf(float lo, float hi) {
    __hip_bfloat162 b = __float22bfloat162_rn(make_float2(lo, hi));
    union { __hip_bfloat162 b2; unsigned int u; } c; c.b2 = b;
    return c.u;
}

// ---------------------------------------------------------------------------
// Kernel T (merged one-time layout work).
//  A1 [0,8192):      v0 (H=256) BCHW f32 -> BHWC bf16, 64ch x 64x tiles
//  A2 [8192,10240):  v1 (H=128)   "
//  A3 [10240,10752): v2 (H=64)    "
//  A4 [10752,11008): v3 (H=32)  32x-wide path
//  B  [11008,13056): Wout(8192,256) -> Wtb(256,8192) bf16
//  C  [13056,13568): {Woff|Wca1|Wsa1} -> WH/WL (512,256) double-bf16
//  D  [13568,15616): qc -> qcH/qcL (2048,256) double-bf16, zero-pad
// ---------------------------------------------------------------------------
__global__ __launch_bounds__(256) void trans_kernel(
    const float* __restrict__ v0, const float* __restrict__ v1,
    const float* __restrict__ v2, const float* __restrict__ v3,
    unsigned short* __restrict__ vt0, unsigned short* __restrict__ vt1,
    unsigned short* __restrict__ vt2, unsigned short* __restrict__ vt3,
    const float* __restrict__ Wout, unsigned short* __restrict__ Wtb,
    const float* __restrict__ Woff, const float* __restrict__ Wca1,
    const float* __restrict__ Wsa1,
    unsigned short* __restrict__ WH, unsigned short* __restrict__ WL,
    const float* __restrict__ qc,
    unsigned short* __restrict__ qcH, unsigned short* __restrict__ qcL)
{
    __shared__ float tile[64][68];   // 68: 16B-aligned rows for b128 LDS writes
    int bid = blockIdx.x;
    const int t = threadIdx.x;

    if (bid < 10752) {
        // ---- 64ch x 64x vectorized transpose (H >= 64) ----
        const float* v; unsigned short* vt; int H; int local;
        if (bid < 8192)       { v = v0; vt = vt0; H = 256; local = bid; }
        else if (bid < 10240) { v = v1; vt = vt1; H = 128; local = bid - 8192; }
        else                  { v = v2; vt = vt2; H = 64;  local = bid - 10240; }
        const int y  = local % H;          local /= H;
        const int xt = local % (H >> 6);   local /= (H >> 6);
        const int ct = local & 3;
        const int b  = local >> 2;

        const int c  = t >> 2;             // channel 0..63
        const int xq = (t & 3) * 16;       // x base (floats)
        const float* src = v + ((size_t)(b * 256 + ct * 64 + c) * H + y) * H + xt * 64 + xq;
        #pragma unroll
        for (int i = 0; i < 4; i++) {
            const float4 f = ((const float4*)src)[i];
            *(float4*)&tile[c][xq + 4 * i] = f;
        }
        __syncthreads();

        const int x  = t >> 2;             // x 0..63
        const int cq = (t & 3) * 16;       // channel base
        unsigned short* dst = vt + (((size_t)(b * H + y) * H + xt * 64 + x) * 256) + ct * 64 + cq;
        #pragma unroll
        for (int half = 0; half < 2; half++) {
            uint4 o;
            unsigned int* op = (unsigned int*)&o;
            #pragma unroll
            for (int j = 0; j < 4; j++) {
                const int cc = cq + half * 8 + 2 * j;
                op[j] = pkbf(tile[cc][x], tile[cc + 1][x]);
            }
            *(uint4*)(dst + half * 8) = o;
        }
    } else if (bid < 11008) {
        // ---- v3 (H=32), 32x-wide path ----
        int local = bid - 10752;
        const int y  = local & 31;  local >>= 5;
        const int ct = local & 3;
        const int b  = local >> 2;
        const float* src = v3 + ((size_t)(b * 256 + ct * 64) * 32 + y) * 32;
        const int xi = t & 31;
        #pragma unroll
        for (int i = 0; i < 8; i++) {
            const int c = (t >> 5) + i * 8;
            tile[c][xi] = src[(size_t)c * 32 * 32 + xi];
        }
        __syncthreads();
        unsigned short* dst = vt3 + (((size_t)(b * 32 + y) * 32) * 256) + ct * 64;
        const int ci = (t & 31) * 2;
        #pragma unroll
        for (int i = 0; i < 4; i++) {
            const int x2 = (t >> 5) + i * 8;
            *(unsigned int*)(dst + (size_t)x2 * 256 + ci) = pkbf(tile[ci][x2], tile[ci + 1][x2]);
        }
    } else if (bid < 13056) {
        // ---- Wout transpose ----
        const int local = bid - 11008;
        const int k0 = (local & 255) * 32, n0 = (local >> 8) * 32;
        float* tl = &tile[0][0];           // use as [32][33]
        #pragma unroll
        for (int i = 0; i < 4; i++) {
            const int ki = (t >> 5) + i * 8;
            tl[ki * 33 + (t & 31)] = Wout[(size_t)(k0 + ki) * 256 + n0 + (t & 31)];
        }
        __syncthreads();
        #pragma unroll
        for (int i = 0; i < 4; i++) {
            const int ni = (t >> 5) + i * 8;
            const int ki = t & 31;
            Wtb[(size_t)(n0 + ni) * KDIM + k0 + ki] = f2bf(tl[ki * 33 + ni]);
        }
    } else if (bid < 13568) {
        const int n = bid - 13056;        // 0..511, thread = k
        float val;
        if (n < 384)      val = Woff[(size_t)t * 384 + n];
        else if (n < 448) val = Wca1[(size_t)t * 64 + (n - 384)];
        else              val = Wsa1[(size_t)t * 64 + (n - 448)];
        const unsigned short hh = f2bf(val);
        WH[(size_t)n * 256 + t] = hh;
        WL[(size_t)n * 256 + t] = f2bf(val - bf2f(hh));
    } else {
        const int q = bid - 13568;        // 0..2047
        const float val = (q < NQ) ? qc[(size_t)q * 256 + t] : 0.f;
        const unsigned short hh = f2bf(val);
        qcH[(size_t)q * 256 + t] = hh;
        qcL[(size_t)q * 256 + t] = f2bf(val - bf2f(hh));
    }
}

// ---------------------------------------------------------------------------
// Kernel A: H(2048,512) = qc(2048,256) @ [Woff|Wca1|Wsa1](256,512)
// double-bf16 (AH*BH + AH*BL + AL*BH), streaming MFMA, no LDS.
// ---------------------------------------------------------------------------
__global__ __launch_bounds__(256) void gemmA_kernel(
    const unsigned short* __restrict__ qcH, const unsigned short* __restrict__ qcL,
    const unsigned short* __restrict__ WH,  const unsigned short* __restrict__ WL,
    float* __restrict__ Hout)               // (2048, 512)
{
    const int m0 = blockIdx.x * 64;
    const int n0 = blockIdx.y * 64;
    const int t  = threadIdx.x;
    const int w    = t >> 6;
    const int lane = t & 63;
    const int mw = (w & 1) * 32;
    const int nw = (w >> 1) * 32;
    const int quad = lane >> 4;
    const int l16  = lane & 15;

    f32x4 acc[2][2] = {};
    #pragma unroll
    for (int pass = 0; pass < 3; pass++) {
        const unsigned short* Ap = (pass == 2) ? qcL : qcH;
        const unsigned short* Bp = (pass == 1) ? WL : WH;
        const unsigned short* ar0 = Ap + (size_t)(m0 + mw + l16) * 256 + quad * 8;
        const unsigned short* ar1 = ar0 + 16 * 256;
        const unsigned short* br0 = Bp + (size_t)(n0 + nw + l16) * 256 + quad * 8;
        const unsigned short* br1 = br0 + 16 * 256;
        #pragma unroll
        for (int k = 0; k < 256; k += 32) {
            const bf16x8 a0 = *(const bf16x8*)(ar0 + k);
            const bf16x8 a1 = *(const bf16x8*)(ar1 + k);
            const bf16x8 b0 = *(const bf16x8*)(br0 + k);
            const bf16x8 b1 = *(const bf16x8*)(br1 + k);
            acc[0][0] = __builtin_amdgcn_mfma_f32_16x16x32_bf16(a0, b0, acc[0][0], 0, 0, 0);
            acc[0][1] = __builtin_amdgcn_mfma_f32_16x16x32_bf16(a0, b1, acc[0][1], 0, 0, 0);
            acc[1][0] = __builtin_amdgcn_mfma_f32_16x16x32_bf16(a1, b0, acc[1][0], 0, 0, 0);
            acc[1][1] = __builtin_amdgcn_mfma_f32_16x16x32_bf16(a1, b1, acc[1][1], 0, 0, 0);
        }
    }
    #pragma unroll
    for (int i = 0; i < 2; i++)
        #pragma unroll
        for (int j = 0; j < 2; j++) {
            const int n = n0 + nw + 16 * j + l16;
            #pragma unroll
            for (int r = 0; r < 4; r++) {
                const int m = m0 + mw + 16 * i + quad * 4 + r;
                Hout[(size_t)m * 512 + n] = acc[i][j][r];
            }
        }
}

// ---------------------------------------------------------------------------
// Kernel F: finish — ca/sa second layers + sigmoid + sampling geometry.
// ---------------------------------------------------------------------------
__global__ __launch_bounds__(256) void finish_kernel(
    const float* __restrict__ Hbuf, const float* __restrict__ xyzrt,
    const float* __restrict__ boff,
    const float* __restrict__ Wca2, const float* __restrict__ Wsa2,
    float* __restrict__ qdata)
{
    const int q0 = blockIdx.x * 8;
    const int t  = threadIdx.x;
    __shared__ float hca[8][64];
    __shared__ float hsa[8][64];
    __shared__ float sas[8][128];

    for (int i = t; i < 1024; i += 256) {
        const int q = i >> 7, j = i & 127;
        const float v = fmaxf(Hbuf[(size_t)(q0 + q) * 512 + 384 + j], 0.f);
        if (j < 64) hca[q][j] = v; else hsa[q][j - 64] = v;
    }
    __syncthreads();

    {   // ca: channel c = t, all 8 queries
        float acc[8] = {};
        for (int j = 0; j < 64; j++) {
            const float wv = Wca2[(size_t)j * 256 + t];
            #pragma unroll
            for (int q = 0; q < 8; q++) acc[q] = fmaf(hca[q][j], wv, acc[q]);
        }
        #pragma unroll
        for (int q = 0; q < 8; q++)
            qdata[(size_t)(q0 + q) * 1024 + 768 + t] = sigf(acc[q]);
    }
    {   // sa
        const int c  = t & 127;
        const int qb = (t >> 7) * 4;
        float acc[4] = {};
        for (int j = 0; j < 64; j++) {
            const float wv = Wsa2[(size_t)j * 128 + c];
            #pragma unroll
            for (int qq = 0; qq < 4; qq++) acc[qq] = fmaf(hsa[qb + qq][j], wv, acc[qq]);
        }
        #pragma unroll
        for (int qq = 0; qq < 4; qq++) sas[qb + qq][c] = sigf(acc[qq]);
    }
    __syncthreads();

    {   // geometry
        const int p  = t & 127;
        const int qb = (t >> 7) * 4;
        #pragma unroll
        for (int qq = 0; qq < 4; qq++) {
            const int q = qb + qq;
            const float* hrow = Hbuf + (size_t)(q0 + q) * 512 + p * 3;
            const float o0 = hrow[0] + boff[p * 3 + 0];
            const float o1 = hrow[1] + boff[p * 3 + 1];
            const float o2 = hrow[2] + boff[p * 3 + 2];
            const float* xr = xyzrt + (size_t)(q0 + q) * 5;
            const float x = xr[0], y = xr[1], z = xr[2], r = xr[3], th = xr[4];
            const float sc  = exp2f(z);
            const float rw  = sc * exp2f(-0.5f * r);
            const float rh  = sc * exp2f( 0.5f * r);
            const float cth = __cosf(th), sth = __sinf(th);
            const float ox = o0 * rw;
            const float oy = o1 * rh;
            float* qd = qdata + (size_t)(q0 + q) * 1024;
            qd[p]       = x + cth * ox - sth * oy;
            qd[128 + p] = y + sth * ox + cth * oy;
            const float sz = z + o2;
            const float sa = sas[q][p];
            #pragma unroll
            for (int l = 0; l < 4; l++) {
                const float d = sz - (float)(2 + l);
                qd[256 + p * 4 + l] = sigf(-0.5f * d * d) * sa;
            }
        }
    }
}

// ---------------------------------------------------------------------------
// Kernel 2: multi-level bilinear sampling from BHWC bf16.
// One wave = 8 points x 64 ch; lane = (pt = lane>>3, c8 = (lane&7)*8).
// Two phases of 2 levels: 8 tap-loads batched before FMA work.
// Accumulation in float2 vectors (v_pk_fma_f32-eligible).
// ---------------------------------------------------------------------------
__global__ __launch_bounds__(256) void sample_kernel(
    const unsigned short* __restrict__ v0, const unsigned short* __restrict__ v1,
    const unsigned short* __restrict__ v2, const unsigned short* __restrict__ v3,
    const float* __restrict__ qdata,
    unsigned short* __restrict__ X)
{
    const int wid  = blockIdx.x * 4 + (threadIdx.x >> 6);
    const int lane = threadIdx.x & 63;
    const int q  = wid >> 4;
    const int pb = (wid & 15) * 8;
    const int pt = lane >> 3;
    const int gp = pb + pt;
    const int g  = gp >> 5;
    const int c8 = (lane & 7) * 8;
    const int b  = (q >= 1000) ? 1 : 0;

    const float* qd = qdata + (size_t)q * 1024;
    const float px = qd[gp];
    const float py = qd[128 + gp];
    const float4 wl4 = *(const float4*)(qd + 256 + gp * 4);
    const float wlv[4] = { wl4.x, wl4.y, wl4.z, wl4.w };

    const unsigned short* vals[4] = { v0, v1, v2, v3 };
    const int cbase = g * 64 + c8;

    f32x2 acc2[4] = {};
    #pragma unroll
    for (int h = 0; h < 2; h++) {
        uint4 d[8];
        float m[8];
        #pragma unroll
        for (int li = 0; li < 2; li++) {
            const int l = h * 2 + li;
            const int   H   = 256 >> l;
            const float inv = 1.0f / (float)(4 << l);
            const float wl  = wlv[l];
            const float ix = px * inv - 0.5f;
            const float iy = py * inv - 0.5f;
            const float x0f = floorf(ix), y0f = floorf(iy);
            const int   x0 = (int)x0f,    y0 = (int)y0f;
            const float fx1 = ix - x0f, fx0 = 1.f - fx1;
            const float fy1 = iy - y0f, fy0 = 1.f - fy1;
            const bool xi0 = (x0 >= 0) & (x0 < H);
            const bool xi1 = (x0 + 1 >= 0) & (x0 + 1 < H);
            const bool yi0 = (y0 >= 0) & (y0 < H);
            const bool yi1 = (y0 + 1 >= 0) & (y0 + 1 < H);
            const int xc0 = min(max(x0, 0), H - 1);
            const int xc1 = min(max(x0 + 1, 0), H - 1);
            const int yc0 = min(max(y0, 0), H - 1);
            const int yc1 = min(max(y0 + 1, 0), H - 1);
            m[li * 4 + 0] = (xi0 & yi0) ? wl * fx0 * fy0 : 0.f;
            m[li * 4 + 1] = (xi1 & yi0) ? wl * fx1 * fy0 : 0.f;
            m[li * 4 + 2] = (xi0 & yi1) ? wl * fx0 * fy1 : 0.f;
            m[li * 4 + 3] = (xi1 & yi1) ? wl * fx1 * fy1 : 0.f;

            const unsigned short* base = vals[l] + (size_t)b * H * H * 256 + cbase;
            const int ry0 = yc0 * H, ry1 = yc1 * H;
            d[li * 4 + 0] = *(const uint4*)(base + (size_t)(ry0 + xc0) * 256);
            d[li * 4 + 1] = *(const uint4*)(base + (size_t)(ry0 + xc1) * 256);
            d[li * 4 + 2] = *(const uint4*)(base + (size_t)(ry1 + xc0) * 256);
            d[li * 4 + 3] = *(const uint4*)(base + (size_t)(ry1 + xc1) * 256);
        }
        #pragma unroll
        for (int i = 0; i < 8; i++) {
            const unsigned int du[4] = { d[i].x, d[i].y, d[i].z, d[i].w };
            const f32x2 mv = { m[i], m[i] };
            #pragma unroll
            for (int j = 0; j < 4; j++) {
                union { unsigned int u; float f; } lo, hi;
                lo.u = du[j] << 16;
                hi.u = du[j] & 0xffff0000u;
                f32x2 t2 = { lo.f, hi.f };
                acc2[j] = acc2[j] + mv * t2;   // pk_fma via contract
            }
        }
    }

    // ca gate + pack + coalesced store
    const float* caf = qd + 768 + cbase;
    const float4 ca0 = *(const float4*)caf;
    const float4 ca1 = *(const float4*)(caf + 4);
    const f32x2 cav[4] = { { ca0.x, ca0.y }, { ca0.z, ca0.w },
                           { ca1.x, ca1.y }, { ca1.z, ca1.w } };
    uint4 o;
    unsigned int* op = (unsigned int*)&o;
    #pragma unroll
    for (int j = 0; j < 4; j++) {
        const f32x2 r = acc2[j] * cav[j];
        op[j] = pkbf(r.x, r.y);
    }
    *(uint4*)(X + (size_t)q * KDIM + pb * 64 + lane * 8) = o;
}

// ---------------------------------------------------------------------------
// Kernel 3: part[z] = X(MPAD,8192) @ Wtb(256,8192)^T — no-LDS streaming MFMA.
// ---------------------------------------------------------------------------
__global__ __launch_bounds__(256) void gemm_kernel(
    const unsigned short* __restrict__ X,    // (MPAD, 8192) bf16
    const unsigned short* __restrict__ Wt,   // (256, 8192) bf16
    float* __restrict__ part)                // (SPLITK, MPAD, 256)
{
    const int m0 = blockIdx.x * 64;
    const int n0 = blockIdx.y * 64;
    const int z  = blockIdx.z;
    const int t  = threadIdx.x;
    const int w    = t >> 6;
    const int lane = t & 63;
    const int mw = (w & 1) * 32;
    const int nw = (w >> 1) * 32;
    const int quad = lane >> 4;
    const int l16  = lane & 15;

    const unsigned short* ar0 = X  + (size_t)(m0 + mw + l16) * KDIM + quad * 8;
    const unsigned short* ar1 = ar0 + (size_t)16 * KDIM;
    const unsigned short* br0 = Wt + (size_t)(n0 + nw + l16) * KDIM + quad * 8;
    const unsigned short* br1 = br0 + (size_t)16 * KDIM;

    f32x4 acc[2][2] = {};
    const int kbase = z * (KDIM / SPLITK);
    #pragma unroll 4
    for (int k = kbase; k < kbase + KDIM / SPLITK; k += 32) {
        const bf16x8 a0 = *(const bf16x8*)(ar0 + k);
        const bf16x8 a1 = *(const bf16x8*)(ar1 + k);
        const bf16x8 b0 = *(const bf16x8*)(br0 + k);
        const bf16x8 b1 = *(const bf16x8*)(br1 + k);
        acc[0][0] = __builtin_amdgcn_mfma_f32_16x16x32_bf16(a0, b0, acc[0][0], 0, 0, 0);
        acc[0][1] = __builtin_amdgcn_mfma_f32_16x16x32_bf16(a0, b1, acc[0][1], 0, 0, 0);
        acc[1][0] = __builtin_amdgcn_mfma_f32_16x16x32_bf16(a1, b0, acc[1][0], 0, 0, 0);
        acc[1][1] = __builtin_amdgcn_mfma_f32_16x16x32_bf16(a1, b1, acc[1][1], 0, 0, 0);
    }

    float* pz = part + (size_t)z * MPAD * EMB;
    #pragma unroll
    for (int i = 0; i < 2; i++)
        #pragma unroll
        for (int j = 0; j < 2; j++) {
            const int n = n0 + nw + 16 * j + l16;
            #pragma unroll
            for (int r = 0; r < 4; r++) {
                const int m = m0 + mw + 16 * i + quad * 4 + r;
                pz[(size_t)m * EMB + n] = acc[i][j][r];
            }
        }
}

// ---------------------------------------------------------------------------
// Kernel 4: out = sum_z part[z] + bias + qc   (fp32, float4)
// ---------------------------------------------------------------------------
__global__ __launch_bounds__(256) void reduce_kernel(
    const float* __restrict__ part, const float* __restrict__ qc,
    const float* __restrict__ bias, float* __restrict__ out)
{
    const int idx = blockIdx.x * 256 + threadIdx.x;
    if (idx >= NQ * 64) return;
    const int m  = idx >> 6;
    const int c4 = idx & 63;
    float4 a = ((const float4*)bias)[c4];
    const float4 qv = ((const float4*)qc)[(size_t)m * 64 + c4];
    a.x += qv.x; a.y += qv.y; a.z += qv.z; a.w += qv.w;
    #pragma unroll
    for (int z = 0; z < SPLITK; z++) {
        const float4 p = ((const float4*)part)[((size_t)z * MPAD + m) * 64 + c4];
        a.x += p.x; a.y += p.y; a.z += p.z; a.w += p.w;
    }
    ((float4*)out)[(size_t)m * 64 + c4] = a;
}

// ---------------------------------------------------------------------------
extern "C" void kernel_launch(void* const* d_in, const int* in_sizes, int n_in,
                              void* d_out, int out_size, void* d_ws, size_t ws_size,
                              hipStream_t stream) {
    (void)in_sizes; (void)n_in; (void)out_size; (void)ws_size;
    const float* v0    = (const float*)d_in[0];
    const float* v1    = (const float*)d_in[1];
    const float* v2    = (const float*)d_in[2];
    const float* v3    = (const float*)d_in[3];
    const float* qc    = (const float*)d_in[4];
    const float* xyzrt = (const float*)d_in[5];
    const float* Woff  = (const float*)d_in[7];
    const float* boff  = (const float*)d_in[8];
    const float* Wca1  = (const float*)d_in[9];
    const float* Wca2  = (const float*)d_in[10];
    const float* Wsa1  = (const float*)d_in[11];
    const float* Wsa2  = (const float*)d_in[12];
    const float* Wout  = (const float*)d_in[13];
    const float* bout  = (const float*)d_in[14];
    float* out = (float*)d_out;

    // ws layout (bytes):
    char* p = (char*)d_ws;
    float* qdata = (float*)p;                 p += (size_t)NQ * 1024 * 4;           //  8.19 MB
    unsigned short* Xb = (unsigned short*)p;  p += (size_t)MPAD * KDIM * 2;         // 33.55 MB
    unsigned short* vt0 = (unsigned short*)p; p += (size_t)2 * 256 * 256 * 256 * 2; // 67.1 MB
    unsigned short* vt1 = (unsigned short*)p; p += (size_t)2 * 128 * 128 * 256 * 2; // 16.8 MB
    unsigned short* vt2 = (unsigned short*)p; p += (size_t)2 * 64 * 64 * 256 * 2;   //  4.2 MB
    unsigned short* vt3 = (unsigned short*)p; p += (size_t)2 * 32 * 32 * 256 * 2;   //  1.05 MB
    unsigned short* Wtb = (unsigned short*)p; p += (size_t)EMB * KDIM * 2;          //  4.2 MB
    float* partb = (float*)p;                 p += (size_t)SPLITK * MPAD * EMB * 4; // 16.8 MB
    float* Hbuf = (float*)p;                  p += (size_t)MPAD * 512 * 4;          //  4.2 MB
    unsigned short* qcH = (unsigned short*)p; p += (size_t)MPAD * 256 * 2;          //  1.05 MB
    unsigned short* qcL = (unsigned short*)p; p += (size_t)MPAD * 256 * 2;          //  1.05 MB
    unsigned short* WHb = (unsigned short*)p; p += (size_t)512 * 256 * 2;           //  0.26 MB
    unsigned short* WLb = (unsigned short*)p;                                        //  0.26 MB

    trans_kernel<<<15616, 256, 0, stream>>>(v0, v1, v2, v3, vt0, vt1, vt2, vt3,
                                            Wout, Wtb, Woff, Wca1, Wsa1,
                                            WHb, WLb, qc, qcH, qcL);
    gemmA_kernel<<<dim3(MPAD / 64, 8), 256, 0, stream>>>(qcH, qcL, WHb, WLb, Hbuf);
    finish_kernel<<<NQ / 8, 256, 0, stream>>>(Hbuf, xyzrt, boff, Wca2, Wsa2, qdata);
    sample_kernel<<<(NQ * 128) / (4 * 8), 256, 0, stream>>>(vt0, vt1, vt2, vt3, qdata, Xb);
    gemm_kernel<<<dim3(MPAD / 64, EMB / 64, SPLITK), 256, 0, stream>>>(Xb, Wtb, partb);
    reduce_kernel<<<(NQ * 64 + 255) / 256, 256, 0, stream>>>(partb, qc, bout, out);
}